// Round 11
// baseline (529.720 us; speedup 1.0000x reference)
//
#include <hip/hip_runtime.h>
#include <math.h>
#include <float.h>

#define BLK 256

typedef __fp16 half2_t __attribute__((ext_vector_type(2)));

static __device__ __forceinline__ half2_t pkh2(float a, float b)
{
    return __builtin_amdgcn_cvt_pkrtz(a, b);   // v_cvt_pkrtz_f16_f32 -> V2h
}

static __device__ __forceinline__ float fdot2(half2_t a, half2_t b, float c)
{
#if __has_builtin(__builtin_amdgcn_fdot2)
    return __builtin_amdgcn_fdot2(a, b, c, false);   // v_dot2_f32_f16: 2 MACs/inst
#else
    return fmaf((float)a[0], (float)b[0], fmaf((float)a[1], (float)b[1], c));
#endif
}

// ---------------------------------------------------------------------------
// K0: fast exclusive scan of both count arrays. One block, 1024 threads.
// ---------------------------------------------------------------------------
__device__ __forceinline__ void scan_one(const int* __restrict__ cnt, int n,
                                         int* __restrict__ starts, int* wsum)
{
    const int t = threadIdx.x;
    const int chunk = (n + 1023) / 1024;
    const int base = t * chunk;

    int sum = 0;
    for (int k = 0; k < chunk; k++) {
        int idx = base + k;
        if (idx < n) sum += cnt[idx];
    }

    const int lane = t & 63, wid = t >> 6;
    int v = sum;
#pragma unroll
    for (int off = 1; off < 64; off <<= 1) {
        int y = __shfl_up(v, off);
        if (lane >= off) v += y;
    }
    if (lane == 63) wsum[wid] = v;
    __syncthreads();
    if (wid == 0) {
        int w = (lane < 16) ? wsum[lane] : 0;
#pragma unroll
        for (int off = 1; off < 16; off <<= 1) {
            int y = __shfl_up(w, off);
            if (lane >= off) w += y;
        }
        if (lane < 16) wsum[lane] = w;
    }
    __syncthreads();

    int thr_excl = ((wid > 0) ? wsum[wid - 1] : 0) + v - sum;
    int run = thr_excl;
    for (int k = 0; k < chunk; k++) {
        int idx = base + k;
        if (idx < n) { starts[idx] = run; run += cnt[idx]; }
    }
    if (t == 0) starts[n] = wsum[15];
    __syncthreads();
}

__global__ __launch_bounds__(1024) void scan2_kernel(
    const int* __restrict__ dag_cnt, int nd,
    const int* __restrict__ obs_cnt, int no,
    int* __restrict__ dag_starts, int* __restrict__ obs_starts)
{
    __shared__ int wsum[16];
    scan_one(dag_cnt, nd, dag_starts, wsum);
    scan_one(obs_cnt, no, obs_starts, wsum);
}

// ---------------------------------------------------------------------------
// K1: expand segment ids to per-node arrays (one block per segment).
// ---------------------------------------------------------------------------
__global__ __launch_bounds__(128) void expand_ids_kernel(
    const int* __restrict__ dag_starts, int nd,
    const int* __restrict__ obs_starts, int no,
    int* __restrict__ dag_ids, int* __restrict__ obs_ids)
{
    int seg = blockIdx.x;
    if (seg < nd) {
        int s = dag_starts[seg], e = dag_starts[seg + 1];
        for (int i = s + threadIdx.x; i < e; i += 128) dag_ids[i] = seg;
    } else {
        int g = seg - nd;
        int s = obs_starts[g], e = obs_starts[g + 1];
        for (int i = s + threadIdx.x; i < e; i += 128) obs_ids[i] = g;
    }
}

// ---------------------------------------------------------------------------
// K2: per-segment layer-1 partials (dag rows 37..68 no bias; glob rows 69..100 +b1).
// These stay FULL FP32 (64 of 101 input dims carry no fp16 error).
// ---------------------------------------------------------------------------
__global__ __launch_bounds__(256) void seg_h1_kernel(
    const float* __restrict__ dag_sum, int nd,
    const float* __restrict__ glob_sum, int no,
    const float* __restrict__ W1, const float* __restrict__ b1,
    float* __restrict__ dag_h1, float* __restrict__ glob_h1)
{
    __shared__ float Wd[32 * 32];
    __shared__ float Wg[32 * 32];
    for (int t = threadIdx.x; t < 32 * 32; t += 256) {
        int k = t / 32, j = t % 32;
        Wd[t] = W1[(size_t)(37 + k) * 32 + j];
        Wg[t] = W1[(size_t)(69 + k) * 32 + j];
    }
    __syncthreads();

    int gid = blockIdx.x * 256 + threadIdx.x;
    int seg = gid / 32;
    int j   = gid % 32;
    if (seg >= nd + no) return;

    const float* srow;
    const float* Wl;
    float acc;
    float* outp;
    if (seg < nd) {
        srow = dag_sum + (size_t)seg * 32;
        Wl = Wd; acc = 0.f;
        outp = dag_h1 + (size_t)seg * 32 + j;
    } else {
        srow = glob_sum + (size_t)(seg - nd) * 32;
        Wl = Wg; acc = b1[j];
        outp = glob_h1 + (size_t)(seg - nd) * 32 + j;
    }
#pragma unroll
    for (int k = 0; k < 32; k++)
        acc = fmaf(srow[k], Wl[k * 32 + j], acc);
    *outp = acc;
}

// ---------------------------------------------------------------------------
// K2b: pack MLP weights into half2 pairs, ALIGNED to the streaming order:
//   W1p pair p: p=0:(x0,x1) p=1:(x2,x3) p=2:(x4,ZERO)
//               p>=3: emb rows (5+2(p-3), 6+2(p-3))  [rows 5..36]
//   W2p: 16 pairs x 16 ; W3p: 8 pairs x 8 ; W4p: 4 pairs
// ---------------------------------------------------------------------------
__global__ __launch_bounds__(256) void pack_weights_kernel(
    const float* __restrict__ W1, const float* __restrict__ W2,
    const float* __restrict__ W3, const float* __restrict__ W4,
    half2_t* __restrict__ W1p, half2_t* __restrict__ W2p,
    half2_t* __restrict__ W3p, half2_t* __restrict__ W4p)
{
    for (int t = threadIdx.x; t < 19 * 32; t += 256) {
        int p = t / 32, j = t % 32;
        float lo, hi;
        if (p == 0)      { lo = W1[0 * 32 + j];  hi = W1[1 * 32 + j]; }
        else if (p == 1) { lo = W1[2 * 32 + j];  hi = W1[3 * 32 + j]; }
        else if (p == 2) { lo = W1[4 * 32 + j];  hi = 0.f; }
        else {
            int r = 5 + 2 * (p - 3);
            lo = W1[(size_t)r * 32 + j];
            hi = W1[(size_t)(r + 1) * 32 + j];
        }
        W1p[t] = pkh2(lo, hi);
    }
    for (int t = threadIdx.x; t < 16 * 16; t += 256) {
        int p = t / 16, j = t % 16;
        W2p[t] = pkh2(W2[(size_t)(2 * p) * 16 + j], W2[(size_t)(2 * p + 1) * 16 + j]);
    }
    for (int t = threadIdx.x; t < 8 * 8; t += 256) {
        int p = t / 8, j = t % 8;
        W3p[t] = pkh2(W3[(size_t)(2 * p) * 8 + j], W3[(size_t)(2 * p + 1) * 8 + j]);
    }
    if (threadIdx.x < 4)
        W4p[threadIdx.x] = pkh2(W4[2 * threadIdx.x], W4[2 * threadIdx.x + 1]);
}

// ---------------------------------------------------------------------------
// K3: main MLP, fp16-dot2, TWO nodes per thread (i, i+BLK).
// Rationale (R10 post-mortem): K3 = ~35us issue + ~100us stall; the stall is
// invariant under scheduling changes and each wave is ~95% stalled. Two
// INDEPENDENT node-pipelines per wave double per-wave work and halve wave
// count -> if the stall is per-wave latency-chain, it halves. Each scalar
// weight (SGPR) also now feeds two dots. Register budget: h1a+h1b=64 f32 +
// per-q transients <=16 -> ~90 VGPR peak (R2's spill came from fp32 full
// arrays; fdot2 halves the weight stream and h-arrays are the only state).
// No launch_bounds min-waves (R2 lesson), no fences (R5 lesson).
// ---------------------------------------------------------------------------
__global__ __launch_bounds__(BLK) void mlp_score_kernel(
    const float* __restrict__ x, const float* __restrict__ emb,
    const float* __restrict__ dag_h1, const float* __restrict__ glob_h1,
    const int* __restrict__ dag_ids, const int* __restrict__ obs_ids,
    const int* __restrict__ mask,
    const half2_t* __restrict__ W1p, const half2_t* __restrict__ W2p,
    const half2_t* __restrict__ W3p, const half2_t* __restrict__ W4p,
    const float* __restrict__ b2, const float* __restrict__ b3,
    const float* __restrict__ b4,
    float* __restrict__ scores, float* __restrict__ blk_m,
    double* __restrict__ blk_s, int N)
{
    const int base = blockIdx.x * (2 * BLK) + threadIdx.x;
    const int i0a = base;
    const int i0b = base + BLK;
    const bool va = (i0a < N);
    const bool vb = (i0b < N);
    const int ia = va ? i0a : (N - 1);
    const int ib = vb ? i0b : (N - 1);

    // --- ids first (gathers depend on them) ---
    const int da = dag_ids[ia], db = dag_ids[ib];
    const int oa = obs_ids[ia], ob = obs_ids[ib];
    const int mka = mask[ia],  mkb = mask[ib];

    // --- h1 init from gathers, per-q streaming (transients die fast) ---
    const float4* dha = (const float4*)(dag_h1 + (size_t)da * 32);
    const float4* gha = (const float4*)(glob_h1 + (size_t)oa * 32);
    const float4* dhb = (const float4*)(dag_h1 + (size_t)db * 32);
    const float4* ghb = (const float4*)(glob_h1 + (size_t)ob * 32);

    float h1a[32], h1b[32];
#pragma unroll
    for (int q = 0; q < 8; q++) {
        float4 dv = dha[q], gv = gha[q];
        h1a[4 * q + 0] = dv.x + gv.x;
        h1a[4 * q + 1] = dv.y + gv.y;
        h1a[4 * q + 2] = dv.z + gv.z;
        h1a[4 * q + 3] = dv.w + gv.w;
        float4 dw = dhb[q], gw = ghb[q];
        h1b[4 * q + 0] = dw.x + gw.x;
        h1b[4 * q + 1] = dw.y + gw.y;
        h1b[4 * q + 2] = dw.z + gw.z;
        h1b[4 * q + 3] = dw.w + gw.w;
    }

    // --- x phase: 3 pair-rows, each weight feeds both nodes ---
    const float* xra = x + (size_t)ia * 5;
    const float* xrb = x + (size_t)ib * 5;
    {
        const half2_t pa0 = pkh2(xra[0], xra[1]);
        const half2_t pb0 = pkh2(xrb[0], xrb[1]);
#pragma unroll
        for (int j = 0; j < 32; j++) {
            const half2_t w = W1p[j];
            h1a[j] = fdot2(pa0, w, h1a[j]);
            h1b[j] = fdot2(pb0, w, h1b[j]);
        }
        const half2_t pa1 = pkh2(xra[2], xra[3]);
        const half2_t pb1 = pkh2(xrb[2], xrb[3]);
#pragma unroll
        for (int j = 0; j < 32; j++) {
            const half2_t w = W1p[32 + j];
            h1a[j] = fdot2(pa1, w, h1a[j]);
            h1b[j] = fdot2(pb1, w, h1b[j]);
        }
        const half2_t pa2 = pkh2(xra[4], 0.f);
        const half2_t pb2 = pkh2(xrb[4], 0.f);
#pragma unroll
        for (int j = 0; j < 32; j++) {
            const half2_t w = W1p[64 + j];
            h1a[j] = fdot2(pa2, w, h1a[j]);
            h1b[j] = fdot2(pb2, w, h1b[j]);
        }
    }

    // --- emb phase: per-q, 2 pair-rows x 2 nodes (weights shared) ---
    const float4* era = (const float4*)(emb + (size_t)ia * 32);
    const float4* erb = (const float4*)(emb + (size_t)ib * 32);
#pragma unroll
    for (int q = 0; q < 8; q++) {
        const float4 ea = era[q];
        const float4 eb = erb[q];
        const half2_t paa = pkh2(ea.x, ea.y);
        const half2_t pab = pkh2(eb.x, eb.y);
#pragma unroll
        for (int j = 0; j < 32; j++) {
            const half2_t w = W1p[(3 + 2 * q) * 32 + j];
            h1a[j] = fdot2(paa, w, h1a[j]);
            h1b[j] = fdot2(pab, w, h1b[j]);
        }
        const half2_t pba = pkh2(ea.z, ea.w);
        const half2_t pbb = pkh2(eb.z, eb.w);
#pragma unroll
        for (int j = 0; j < 32; j++) {
            const half2_t w = W1p[(4 + 2 * q) * 32 + j];
            h1a[j] = fdot2(pba, w, h1a[j]);
            h1b[j] = fdot2(pbb, w, h1b[j]);
        }
    }

#pragma unroll
    for (int j = 0; j < 32; j++) {
        h1a[j] = fmaxf(h1a[j], 0.f);
        h1b[j] = fmaxf(h1b[j], 0.f);
    }

    // --- layer 2: 32 -> 16 ---
    float h2a[16], h2b[16];
#pragma unroll
    for (int j = 0; j < 16; j++) { const float bb = b2[j]; h2a[j] = bb; h2b[j] = bb; }
#pragma unroll
    for (int p = 0; p < 16; p++) {
        const half2_t hpa = pkh2(h1a[2 * p], h1a[2 * p + 1]);
        const half2_t hpb = pkh2(h1b[2 * p], h1b[2 * p + 1]);
#pragma unroll
        for (int j = 0; j < 16; j++) {
            const half2_t w = W2p[p * 16 + j];
            h2a[j] = fdot2(hpa, w, h2a[j]);
            h2b[j] = fdot2(hpb, w, h2b[j]);
        }
    }
#pragma unroll
    for (int j = 0; j < 16; j++) {
        h2a[j] = fmaxf(h2a[j], 0.f);
        h2b[j] = fmaxf(h2b[j], 0.f);
    }

    // --- layer 3: 16 -> 8 ---
    float h3a[8], h3b[8];
#pragma unroll
    for (int j = 0; j < 8; j++) { const float bb = b3[j]; h3a[j] = bb; h3b[j] = bb; }
#pragma unroll
    for (int p = 0; p < 8; p++) {
        const half2_t hpa = pkh2(h2a[2 * p], h2a[2 * p + 1]);
        const half2_t hpb = pkh2(h2b[2 * p], h2b[2 * p + 1]);
#pragma unroll
        for (int j = 0; j < 8; j++) {
            const half2_t w = W3p[p * 8 + j];
            h3a[j] = fdot2(hpa, w, h3a[j]);
            h3b[j] = fdot2(hpb, w, h3b[j]);
        }
    }
#pragma unroll
    for (int j = 0; j < 8; j++) {
        h3a[j] = fmaxf(h3a[j], 0.f);
        h3b[j] = fmaxf(h3b[j], 0.f);
    }

    // --- layer 4 ---
    float sa = b4[0], sb = b4[0];
#pragma unroll
    for (int p = 0; p < 4; p++) {
        const half2_t w = W4p[p];
        sa = fdot2(pkh2(h3a[2 * p], h3a[2 * p + 1]), w, sa);
        sb = fdot2(pkh2(h3b[2 * p], h3b[2 * p + 1]), w, sb);
    }

    const bool livea = va && (mka != 0);
    const bool liveb = vb && (mkb != 0);
    if (va) scores[i0a] = livea ? sa : -FLT_MAX;
    if (vb) scores[i0b] = liveb ? sb : -FLT_MAX;

    // --- merge the thread's pair -> (m, s) ---
    float ma = livea ? sa : -INFINITY;
    float mb = liveb ? sb : -INFINITY;
    float m = fmaxf(ma, mb);
    double sd = 0.0;
    if (ma > -INFINITY) sd += (double)expf(ma - m);
    if (mb > -INFINITY) sd += (double)expf(mb - m);

    // --- wave shuffle reduce, then tiny LDS merge ---
#pragma unroll
    for (int off = 32; off > 0; off >>= 1) {
        float  mo = __shfl_down(m, off);
        double so = __shfl_down(sd, off);
        float M = fmaxf(m, mo);
        double out = 0.0;
        if (m  > -INFINITY) out += sd * (double)expf(m  - M);
        if (mo > -INFINITY) out += so * (double)expf(mo - M);
        m = M; sd = out;
    }
    __shared__ float  mw[BLK / 64];
    __shared__ double sw[BLK / 64];
    const int lane = threadIdx.x & 63, wid = threadIdx.x >> 6;
    if (lane == 0) { mw[wid] = m; sw[wid] = sd; }
    __syncthreads();
    if (threadIdx.x == 0) {
        float M = mw[0]; double S = sw[0];
#pragma unroll
        for (int w = 1; w < BLK / 64; w++) {
            float mbw = mw[w]; double sbw = sw[w];
            float Mn = fmaxf(M, mbw);
            double out = 0.0;
            if (M   > -INFINITY) out += S   * (double)expf(M   - Mn);
            if (mbw > -INFINITY) out += sbw * (double)expf(mbw - Mn);
            M = Mn; S = out;
        }
        blk_m[blockIdx.x] = M;
        blk_s[blockIdx.x] = S;
    }
}

// ---------------------------------------------------------------------------
// K4: merge per-block (m, s) pairs -> gmax, Z. One block.
// ---------------------------------------------------------------------------
__global__ __launch_bounds__(1024) void merge_kernel(
    const float* __restrict__ bm, const double* __restrict__ bs, int n,
    float* __restrict__ gmax, double* __restrict__ Z)
{
    float m = -INFINITY;
    double s = 0.0;
    for (int i = threadIdx.x; i < n; i += 1024) {
        float mb = bm[i]; double sb = bs[i];
        float M = fmaxf(m, mb);
        double out = 0.0;
        if (m  > -INFINITY) out += s  * (double)expf(m  - M);
        if (mb > -INFINITY) out += sb * (double)expf(mb - M);
        m = M; s = out;
    }
    __shared__ float  mred[1024];
    __shared__ double sred[1024];
    mred[threadIdx.x] = m;
    sred[threadIdx.x] = s;
    __syncthreads();
    for (int off = 512; off > 0; off >>= 1) {
        if (threadIdx.x < off) {
            float ma = mred[threadIdx.x], mb = mred[threadIdx.x + off];
            double sa = sred[threadIdx.x], sb = sred[threadIdx.x + off];
            float M = fmaxf(ma, mb);
            double out = 0.0;
            if (ma > -INFINITY) out += sa * (double)expf(ma - M);
            if (mb > -INFINITY) out += sb * (double)expf(mb - M);
            mred[threadIdx.x] = M;
            sred[threadIdx.x] = out;
        }
        __syncthreads();
    }
    if (threadIdx.x == 0) { *gmax = mred[0]; *Z = sred[0]; }
}

// ---------------------------------------------------------------------------
// K5: finalize out[i] = exp(s - gmax) / Z  (masked -FLT_MAX -> exactly 0).
// ---------------------------------------------------------------------------
__global__ __launch_bounds__(BLK) void finalize_kernel(
    const float* __restrict__ scores, int N,
    const float* __restrict__ gmaxp, const double* __restrict__ Zp,
    float* __restrict__ outp)
{
    const float gm = *gmaxp;
    const float rZ = (float)(1.0 / *Zp);
    int i = blockIdx.x * BLK + threadIdx.x;
    if (i < N) outp[i] = expf(scores[i] - gm) * rZ;
}

// ---------------------------------------------------------------------------
extern "C" void kernel_launch(void* const* d_in, const int* in_sizes, int n_in,
                              void* d_out, int out_size, void* d_ws, size_t ws_size,
                              hipStream_t stream)
{
    const float* x        = (const float*)d_in[0];
    const float* emb      = (const float*)d_in[1];
    const float* dag_sum  = (const float*)d_in[2];
    const float* glob_sum = (const float*)d_in[3];
    const int*   dag_cnt  = (const int*)d_in[4];
    const int*   obs_cnt  = (const int*)d_in[5];
    const int*   mask     = (const int*)d_in[6];   // bool staged as int32
    const float* W1 = (const float*)d_in[7];
    const float* b1 = (const float*)d_in[8];
    const float* W2 = (const float*)d_in[9];
    const float* b2 = (const float*)d_in[10];
    const float* W3 = (const float*)d_in[11];
    const float* b3 = (const float*)d_in[12];
    const float* W4 = (const float*)d_in[13];
    const float* b4 = (const float*)d_in[14];
    float* outp = (float*)d_out;

    const int N  = in_sizes[0] / 5;   // 2,000,000
    const int nd = in_sizes[4];       // 20,000
    const int no = in_sizes[5];       // 1,000

    const int main_blocks = (N + 2 * BLK - 1) / (2 * BLK);   // 3907

    // --- workspace layout (16B aligned slices) ---
    char* ws = (char*)d_ws;
    size_t off = 0;
    auto alloc = [&](size_t bytes) {
        void* p = ws + off;
        off += (bytes + 15) & ~(size_t)15;
        return p;
    };
    int*     dag_starts = (int*)    alloc((size_t)(nd + 1) * sizeof(int));
    int*     obs_starts = (int*)    alloc((size_t)(no + 1) * sizeof(int));
    int*     dag_ids    = (int*)    alloc((size_t)N * sizeof(int));
    int*     obs_ids    = (int*)    alloc((size_t)N * sizeof(int));
    float*   dag_h1     = (float*)  alloc((size_t)nd * 32 * sizeof(float));
    float*   glob_h1    = (float*)  alloc((size_t)no * 32 * sizeof(float));
    float*   scores     = (float*)  alloc((size_t)N * sizeof(float));
    float*   blk_m      = (float*)  alloc((size_t)main_blocks * sizeof(float));
    double*  blk_s      = (double*) alloc((size_t)main_blocks * sizeof(double));
    float*   gmax       = (float*)  alloc(sizeof(float));
    double*  Z          = (double*) alloc(sizeof(double));
    half2_t* W1p        = (half2_t*)alloc((size_t)19 * 32 * sizeof(half2_t));
    half2_t* W2p        = (half2_t*)alloc((size_t)16 * 16 * sizeof(half2_t));
    half2_t* W3p        = (half2_t*)alloc((size_t)8 * 8 * sizeof(half2_t));
    half2_t* W4p        = (half2_t*)alloc((size_t)4 * sizeof(half2_t));
    (void)ws_size;

    // K0: prefix scans
    scan2_kernel<<<1, 1024, 0, stream>>>(dag_cnt, nd, obs_cnt, no, dag_starts, obs_starts);

    // K2b: pack weights to half2 (independent of K0/K1)
    pack_weights_kernel<<<1, 256, 0, stream>>>(W1, W2, W3, W4, W1p, W2p, W3p, W4p);

    // K1: expand segment ids to nodes
    expand_ids_kernel<<<nd + no, 128, 0, stream>>>(dag_starts, nd, obs_starts, no, dag_ids, obs_ids);

    // K2: per-segment layer-1 partials (fp32)
    {
        int total = (nd + no) * 32;
        seg_h1_kernel<<<(total + 255) / 256, 256, 0, stream>>>(
            dag_sum, nd, glob_sum, no, W1, b1, dag_h1, glob_h1);
    }

    // K3: main MLP (fp16 dot2, 2 nodes/thread) + scores + softmax partials
    mlp_score_kernel<<<main_blocks, BLK, 0, stream>>>(
        x, emb, dag_h1, glob_h1, dag_ids, obs_ids, mask,
        W1p, W2p, W3p, W4p, b2, b3, b4, scores, blk_m, blk_s, N);

    // K4: merge -> gmax, Z
    merge_kernel<<<1, 1024, 0, stream>>>(blk_m, blk_s, main_blocks, gmax, Z);

    // K5: finalize
    finalize_kernel<<<(N + BLK - 1) / BLK, BLK, 0, stream>>>(scores, N, gmax, Z, outp);
}